// Round 9
// baseline (523.212 us; speedup 1.0000x reference)
//
#include <hip/hip_runtime.h>

#define EPS_BN 1e-5f

typedef __attribute__((ext_vector_type(8))) short sh8;
typedef __attribute__((ext_vector_type(4))) short sh4;
typedef __attribute__((ext_vector_type(4))) float f32x4;

// ================= fp32 workspace arena =================
// [0, ~27.5MB): bf16 hi/lo alphaT/projT scratch (tbuf) + bf16 Wlin — dead before convs run.
static const size_t PART_OFF = 2645784;   // split-K partials (conv L4/L5 phase)
static const size_t PRE_OFF  = 6258456;   // pre-BN flat conv output (max 2408448)
static const size_t OUT5_OFF = 8666904;   // 110592 L5 pre-BN flat
static const size_t H_OFF    = 8777496;   // 110592 fc1 input (NCDHW flat)
static const size_t BNP_OFF  = 8888088;   // 5 regions x (64 rows x 768) = 245760 bn partials
static const size_t H1_OFF   = 9133848;   // 1024 fc1 output
static const size_t WS_TOT   = 9134872;   // ~36.5 MB
__device__ __align__(256) float g_ws[WS_TOT];

// bf16 activation arena (halo-padded NDHWC)
static const size_t XIN_OFF = 0;         // [2][18][114][114][4]  = 1871424
static const size_t A1_OFF  = 1871424;   // [2][18][58][58][24]   = 2905344
static const size_t A2_OFF  = 4776768;   // [2][18][30][30][48]   = 1555200
static const size_t A3_OFF  = 6331968;   // [2][18][16][16][96]   = 884736
static const size_t A4_OFF  = 7216704;   // [2][18][9][9][192]    = 559872
static const size_t AR_TOT  = 7776576;
__device__ __align__(256) unsigned short g_act[AR_TOT];

// bf16 conv weights [NPAD][KPAD], k-order = s*CPAD+c
static const size_t WB_OFF[5] = {0, 4096, 36352, 162304, 659968};
static const size_t WB_TOT    = 2650624;
__device__ __align__(256) unsigned short g_wb[WB_TOT];

__device__ inline unsigned short f2bf(float v) {
    unsigned u = __float_as_uint(v);
    return (unsigned short)((u + 0x7fffu + ((u >> 16) & 1u)) >> 16);
}
__device__ inline float bf2f(unsigned short h) {
    return __uint_as_float(((unsigned)h) << 16);
}

// ================= merged init (convert+zero) + prep (transpose/split-convert) =================
// blocks [0, prepBlocks): transpose+convert alpha/proj fp32 [512][W] -> bf16 hi/lo [Wpad64][512]
// blocks [prepBlocks, ...): zero A1..A4 halos + zero g_wb + zero 5x bnp + convert x -> xin
struct InitPrepArgs {
    const float* src[10];
    int W[10];
    int dstrow[10];
    int start[11];
    int rowtot;          // lo-plane row offset
    int prepBlocks;
    const float* x;
    unsigned short* xp;
    float* bnp;          // 245760 floats (5 regions)
    int4* zp; int nz;
    int4* wbz; int nwb;
};

__global__ __launch_bounds__(256) void init_prep(InitPrepArgs a, unsigned short* __restrict__ dst)
{
    __shared__ unsigned short tileh[32 * 72];
    __shared__ unsigned short tilel[32 * 72];
    const int tid = threadIdx.x;

    if (blockIdx.x >= a.prepBlocks) {
        // ---- init path ----
        const int i = (blockIdx.x - a.prepBlocks) * 256 + tid;
        if (i < a.nz) a.zp[i] = make_int4(0, 0, 0, 0);
        if (i < a.nwb) a.wbz[i] = make_int4(0, 0, 0, 0);
        if (i < 245760) a.bnp[i] = 0.f;
        if (i >= 1871424) return;
        const int c = i & 3;
        int t = i >> 2;
        const int xx = t % 114; t /= 114;
        const int yy = t % 114; t /= 114;
        const int zz = t % 18;
        const int b  = t / 18;
        float v = 0.f;
        if (c < 3 && (unsigned)(zz - 1) < 16u && (unsigned)(yy - 1) < 112u && (unsigned)(xx - 1) < 112u)
            v = a.x[(((size_t)b * 3 + c) * 16 + (zz - 1)) * 12544 + (yy - 1) * 112 + (xx - 1)];
        a.xp[i] = f2bf(v);
        return;
    }

    // ---- prep path ----
    int m = 0;
    {
        const int bx = blockIdx.x;
        while (m < 9 && bx >= a.start[m + 1]) ++m;
    }
    const int t  = blockIdx.x - a.start[m];
    const int tw = t >> 4, tp = t & 15;
    const int p0 = tp * 32, w0 = tw * 64;
    const int W = a.W[m];
    const float* __restrict__ src = a.src[m];

    #pragma unroll
    for (int e = 0; e < 8; ++e) {
        const int idx = tid + e * 256;        // 0..2047
        const int w = idx & 63, pr = idx >> 6;
        const int gw = w0 + w;
        float v = 0.f;
        if (gw < W) v = src[(size_t)(p0 + pr) * W + gw];
        const unsigned short hh = f2bf(v);
        tileh[pr * 72 + w] = hh;
        tilel[pr * 72 + w] = f2bf(v - bf2f(hh));
    }
    __syncthreads();
    {
        const int wr = tid >> 2, pg = (tid & 3) * 8;
        sh8 packh, packl;
        #pragma unroll
        for (int e = 0; e < 8; ++e) {
            packh[e] = (short)tileh[(pg + e) * 72 + wr];
            packl[e] = (short)tilel[(pg + e) * 72 + wr];
        }
        const size_t rh = (size_t)a.dstrow[m] + w0 + wr;
        *(sh8*)&dst[rh * 512 + p0 + pg] = packh;
        *(sh8*)&dst[(rh + a.rowtot) * 512 + p0 + pg] = packl;
    }
}

// ================= MFMA fuse v3: LDS-staged, 2-phase, (o-tile x k-tile) grid =================
struct Fuse3Args {
    int aoff[5], poff[5];    // hi-plane row offsets into tbuf
    int woff[5];             // ushort offset into Wlin (rows = NPAD)
    int KL[5];               // linear padded K (= KT*64)
    int noft[5];             // total o-frags = ceil(CO/16)
    int kt[5];               // k-tiles per layer
    int start[6];            // block prefix = cumsum(OT*KT)
    int rowtot;              // lo-plane row offset
};

__global__ __launch_bounds__(256) void fuse_mfma(const unsigned short* __restrict__ tb,
                                                 unsigned short* __restrict__ wlin,
                                                 Fuse3Args a)
{
    __shared__ __align__(16) unsigned short Ah[2][64 * 40];
    __shared__ __align__(16) unsigned short Al[2][64 * 40];
    __shared__ __align__(16) unsigned short Bh[2][64 * 40];
    __shared__ __align__(16) unsigned short Bl[2][64 * 40];

    int l = 0;
    {
        const int bx = blockIdx.x;
        while (l < 4 && bx >= a.start[l + 1]) ++l;
    }
    const int idx = blockIdx.x - a.start[l];
    const int ot = idx / a.kt[l];
    const int kt = idx % a.kt[l];
    const int tid = threadIdx.x;
    const int lane = tid & 63;
    const int wv = tid >> 6;
    const size_t LOFF = (size_t)a.rowtot * 512;

    const int srow = tid >> 2, spg = (tid & 3) * 8;
    const unsigned short* asrc = tb + ((size_t)(a.aoff[l] + ot * 64 + srow)) * 512 + spg;
    const unsigned short* bsrc = tb + ((size_t)(a.poff[l] + kt * 64 + srow)) * 512 + spg;
    const int sidx = srow * 40 + spg;

    f32x4 acc[4];
    #pragma unroll
    for (int i = 0; i < 4; ++i) acc[i] = (f32x4){0.f, 0.f, 0.f, 0.f};

    sh8 rah, ral, rbh, rbl;

    rah = *(const sh8*)(asrc);
    ral = *(const sh8*)(asrc + LOFF);
    rbh = *(const sh8*)(bsrc);
    rbl = *(const sh8*)(bsrc + LOFF);
    *(sh8*)&Ah[0][sidx] = rah;
    *(sh8*)&Al[0][sidx] = ral;
    *(sh8*)&Bh[0][sidx] = rbh;
    *(sh8*)&Bl[0][sidx] = rbl;
    __syncthreads();

    const int fr = (wv * 16 + (lane & 15)) * 40 + (lane >> 4) * 8;
    int cur = 0;
    for (int s = 0; s < 16; ++s) {
        if (s + 1 < 16) {
            const int pn = (s + 1) * 32;
            rah = *(const sh8*)(asrc + pn);
            ral = *(const sh8*)(asrc + LOFF + pn);
            rbh = *(const sh8*)(bsrc + pn);
            rbl = *(const sh8*)(bsrc + LOFF + pn);
        }
        const sh8 ah  = *(const sh8*)&Ah[cur][fr];
        const sh8 alo = *(const sh8*)&Al[cur][fr];
        #pragma unroll
        for (int nt = 0; nt < 4; ++nt) {
            const int bidx = (nt * 16 + (lane & 15)) * 40 + (lane >> 4) * 8;
            const sh8 bh = *(const sh8*)&Bh[cur][bidx];
            const sh8 bl = *(const sh8*)&Bl[cur][bidx];
            acc[nt] = __builtin_amdgcn_mfma_f32_16x16x32_bf16(ah, bh, acc[nt], 0, 0, 0);
            acc[nt] = __builtin_amdgcn_mfma_f32_16x16x32_bf16(ah, bl, acc[nt], 0, 0, 0);
            acc[nt] = __builtin_amdgcn_mfma_f32_16x16x32_bf16(alo, bh, acc[nt], 0, 0, 0);
        }
        if (s + 1 < 16) {
            *(sh8*)&Ah[cur ^ 1][sidx] = rah;
            *(sh8*)&Al[cur ^ 1][sidx] = ral;
            *(sh8*)&Bh[cur ^ 1][sidx] = rbh;
            *(sh8*)&Bl[cur ^ 1][sidx] = rbl;
        }
        __syncthreads();
        cur ^= 1;
    }

    const int f = ot * 4 + wv;
    if (f < a.noft[l]) {
        const int KL = a.KL[l];
        unsigned short* wrow = wlin + a.woff[l];
        #pragma unroll
        for (int nt = 0; nt < 4; ++nt) {
            const int k = kt * 64 + nt * 16 + (lane & 15);
            #pragma unroll
            for (int j = 0; j < 4; ++j) {
                const int o = f * 16 + (lane >> 4) * 4 + j;
                wrow[(size_t)o * KL + k] = f2bf(acc[nt][j]);
            }
        }
    }
}

// ================= reorder: Wlin[o][k] -> Wb[o][s*CPAD+c], coalesced row writes via LDS =================
struct ReordBArgs {
    int woff[5], wboff[5];
    int K[5], KL[5], KP[5], CP[5];
    int start[6];     // prefix over CO
};

__global__ __launch_bounds__(256) void reorder_b(const unsigned short* __restrict__ wlin,
                                                 unsigned short* __restrict__ wb,
                                                 ReordBArgs a)
{
    __shared__ __align__(16) unsigned short lds[5184];
    int l = 0;
    {
        const int bx = blockIdx.x;
        while (l < 4 && bx >= a.start[l + 1]) ++l;
    }
    const int o = blockIdx.x - a.start[l];
    const int K = a.K[l], KL = a.KL[l], KP = a.KP[l], CP = a.CP[l];
    const int tid = threadIdx.x;
    for (int i = tid; i < KP; i += 256) lds[i] = 0;
    __syncthreads();
    const unsigned short* src = wlin + a.woff[l] + (size_t)o * KL;
    for (int k = tid; k < K; k += 256) {
        const int c = k / 27, s = k - c * 27;
        lds[s * CP + c] = src[k];
    }
    __syncthreads();
    unsigned short* drow = wb + a.wboff[l] + (size_t)o * KP;
    for (int i = tid * 8; i < KP; i += 2048)
        *(sh8*)&drow[i] = *(const sh8*)&lds[i];
}

// ================= implicit-GEMM MFMA conv + clamp(1+x,0) + pool(1,2,2) + fused BN stats =================
// 128-row M-tile, 2-phase pipeline, one barrier per 32-k step. bnp is the per-layer region.
template<int CPAD, int COUT, int KPAD, int HI, int WI, int HP, int WP, int NBLK, int SPLIT>
__global__ __launch_bounds__(256) void conv_mfma(
    const unsigned short* __restrict__ in, const unsigned short* __restrict__ Wb,
    float* __restrict__ outf, float* __restrict__ part, float* __restrict__ bnp)
{
    constexpr int NT = NBLK / 16;
    constexpr int HI2 = HI + 2, WI2 = WI + 2;
    constexpr bool C8 = (CPAD % 8 == 0);
    constexpr int TABN = C8 ? KPAD / 8 : KPAD / 4;
    constexpr int NSTEP = KPAD / 32 / SPLIT;
    constexpr int MTOT = 2 * 16 * HP * WP * 4;
    constexpr bool BONCE = (NBLK * KPAD * 2 <= 16384);   // L1 only
    constexpr int BROW = BONCE ? (KPAD + 8) : 40;        // B row stride (shorts)
    constexpr int BS_ELEMS = BONCE ? NBLK * BROW : 2 * NBLK * 40;

    __shared__ __align__(16) unsigned short As[2][128 * 40];
    __shared__ __align__(16) unsigned short Bs[BS_ELEMS];
    __shared__ int tab[TABN];
    __shared__ float bs[(SPLIT == 1) ? 2 * NBLK : 1];

    const int tid = threadIdx.x;
    const int lane = tid & 63;
    const int wv = tid >> 6;
    const int blk_m = blockIdx.x;
    const int oc0 = blockIdx.y * NBLK;
    const int kc = (SPLIT > 1) ? blockIdx.z : 0;

    for (int i = tid; i < TABN; i += 256) {
        const int k = i * (C8 ? 8 : 4);
        const int s = k / CPAD, c = k % CPAD;
        tab[i] = (s < 27) ? ((((s / 9) * HI2 + (s % 9) / 3) * WI2 + (s % 3)) * CPAD + c) : -1;
    }

    if constexpr (BONCE) {
        for (int i = tid; i < NBLK * KPAD / 8; i += 256) {
            const int r = i / (KPAD / 8), kk = i - r * (KPAD / 8);
            *(sh8*)&Bs[r * BROW + kk * 8] = *(const sh8*)&Wb[(size_t)(oc0 + r) * KPAD + kk * 8];
        }
    }

    // A-staging mapping: thread stages row srow = tid>>1, half = tid&1
    const int srow = tid >> 1;
    const int half = tid & 1;
    const int m_g = blk_m * 128 + srow;
    const int pooled_s = m_g >> 2, sub_s = m_g & 3;
    const int pw_g = pooled_s % WP;
    const int ph_g = (pooled_s / WP) % HP;
    const int d_g  = (pooled_s / (WP * HP)) & 15;
    const int b_g  = pooled_s / (WP * HP * 16);
    const int h_g = 2 * ph_g + (sub_s >> 1);
    const int w_g = 2 * pw_g + (sub_s & 1);
    const size_t base_m = ((((size_t)b_g * 18 + d_g) * HI2 + h_g) * WI2 + w_g) * CPAD;

    const int brow = tid >> 2, bcc = tid & 3;
    const bool bload = (tid < NBLK * 4);

    f32x4 acc[2][NT];
    #pragma unroll
    for (int mf = 0; mf < 2; ++mf)
        #pragma unroll
        for (int i = 0; i < NT; ++i) acc[mf][i] = (f32x4){0.f, 0.f, 0.f, 0.f};

    const int k_begin = kc * NSTEP * 32;

    sh8 aA0, aA1;
    sh4 aP0, aP1, aP2, aP3;
    sh8 brg;

    __syncthreads();  // tab (and BONCE B) visible

    {
        const int k0 = k_begin;
        if constexpr (C8) {
            const int o0 = tab[(k0 >> 3) + half * 2];
            const int o1 = tab[(k0 >> 3) + half * 2 + 1];
            aA0 = (sh8){0, 0, 0, 0, 0, 0, 0, 0};
            aA1 = (sh8){0, 0, 0, 0, 0, 0, 0, 0};
            if (o0 >= 0) aA0 = *(const sh8*)(in + base_m + o0);
            if (o1 >= 0) aA1 = *(const sh8*)(in + base_m + o1);
            *(sh8*)&As[0][srow * 40 + (half * 2) * 8]     = aA0;
            *(sh8*)&As[0][srow * 40 + (half * 2 + 1) * 8] = aA1;
        } else {
            const int t0 = tab[(k0 >> 2) + half * 4];
            const int t1 = tab[(k0 >> 2) + half * 4 + 1];
            const int t2 = tab[(k0 >> 2) + half * 4 + 2];
            const int t3 = tab[(k0 >> 2) + half * 4 + 3];
            aP0 = (sh4){0, 0, 0, 0}; aP1 = (sh4){0, 0, 0, 0};
            aP2 = (sh4){0, 0, 0, 0}; aP3 = (sh4){0, 0, 0, 0};
            if (t0 >= 0) aP0 = *(const sh4*)(in + base_m + t0);
            if (t1 >= 0) aP1 = *(const sh4*)(in + base_m + t1);
            if (t2 >= 0) aP2 = *(const sh4*)(in + base_m + t2);
            if (t3 >= 0) aP3 = *(const sh4*)(in + base_m + t3);
            *(sh4*)&As[0][srow * 40 + (half * 4) * 4]     = aP0;
            *(sh4*)&As[0][srow * 40 + (half * 4 + 1) * 4] = aP1;
            *(sh4*)&As[0][srow * 40 + (half * 4 + 2) * 4] = aP2;
            *(sh4*)&As[0][srow * 40 + (half * 4 + 3) * 4] = aP3;
        }
        if constexpr (!BONCE) {
            if (bload) {
                brg = *(const sh8*)&Wb[(size_t)(oc0 + brow) * KPAD + k0 + bcc * 8];
                *(sh8*)&Bs[0 + brow * 40 + bcc * 8] = brg;
            }
        }
    }
    __syncthreads();

    int cur = 0;
    for (int s = 0; s < NSTEP; ++s) {
        const int k0 = k_begin + s * 32;
        if (s + 1 < NSTEP) {
            const int kn = k0 + 32;
            if constexpr (C8) {
                const int o0 = tab[(kn >> 3) + half * 2];
                const int o1 = tab[(kn >> 3) + half * 2 + 1];
                aA0 = (sh8){0, 0, 0, 0, 0, 0, 0, 0};
                aA1 = (sh8){0, 0, 0, 0, 0, 0, 0, 0};
                if (o0 >= 0) aA0 = *(const sh8*)(in + base_m + o0);
                if (o1 >= 0) aA1 = *(const sh8*)(in + base_m + o1);
            } else {
                const int t0 = tab[(kn >> 2) + half * 4];
                const int t1 = tab[(kn >> 2) + half * 4 + 1];
                const int t2 = tab[(kn >> 2) + half * 4 + 2];
                const int t3 = tab[(kn >> 2) + half * 4 + 3];
                aP0 = (sh4){0, 0, 0, 0}; aP1 = (sh4){0, 0, 0, 0};
                aP2 = (sh4){0, 0, 0, 0}; aP3 = (sh4){0, 0, 0, 0};
                if (t0 >= 0) aP0 = *(const sh4*)(in + base_m + t0);
                if (t1 >= 0) aP1 = *(const sh4*)(in + base_m + t1);
                if (t2 >= 0) aP2 = *(const sh4*)(in + base_m + t2);
                if (t3 >= 0) aP3 = *(const sh4*)(in + base_m + t3);
            }
            if constexpr (!BONCE) {
                if (bload) brg = *(const sh8*)&Wb[(size_t)(oc0 + brow) * KPAD + kn + bcc * 8];
            }
        }
        const sh8 af0 = *(const sh8*)&As[cur][(wv * 16 + (lane & 15)) * 40 + (lane >> 4) * 8];
        const sh8 af1 = *(const sh8*)&As[cur][(64 + wv * 16 + (lane & 15)) * 40 + (lane >> 4) * 8];
        #pragma unroll
        for (int nt = 0; nt < NT; ++nt) {
            sh8 bf;
            if constexpr (BONCE)
                bf = *(const sh8*)&Bs[(nt * 16 + (lane & 15)) * BROW + k0 + (lane >> 4) * 8];
            else
                bf = *(const sh8*)&Bs[cur * NBLK * 40 + (nt * 16 + (lane & 15)) * 40 + (lane >> 4) * 8];
            acc[0][nt] = __builtin_amdgcn_mfma_f32_16x16x32_bf16(af0, bf, acc[0][nt], 0, 0, 0);
            acc[1][nt] = __builtin_amdgcn_mfma_f32_16x16x32_bf16(af1, bf, acc[1][nt], 0, 0, 0);
        }
        if (s + 1 < NSTEP) {
            if constexpr (C8) {
                *(sh8*)&As[cur ^ 1][srow * 40 + (half * 2) * 8]     = aA0;
                *(sh8*)&As[cur ^ 1][srow * 40 + (half * 2 + 1) * 8] = aA1;
            } else {
                *(sh4*)&As[cur ^ 1][srow * 40 + (half * 4) * 4]     = aP0;
                *(sh4*)&As[cur ^ 1][srow * 40 + (half * 4 + 1) * 4] = aP1;
                *(sh4*)&As[cur ^ 1][srow * 40 + (half * 4 + 2) * 4] = aP2;
                *(sh4*)&As[cur ^ 1][srow * 40 + (half * 4 + 3) * 4] = aP3;
            }
            if constexpr (!BONCE) {
                if (bload) *(sh8*)&Bs[(cur ^ 1) * NBLK * 40 + brow * 40 + bcc * 8] = brg;
            }
        }
        __syncthreads();
        cur ^= 1;
    }

    const int q = lane >> 4;
    const int nloc = lane & 15;
    if constexpr (SPLIT == 1) {
        for (int i = tid; i < 2 * NBLK; i += 256) bs[i] = 0.f;
        __syncthreads();
        #pragma unroll
        for (int mf = 0; mf < 2; ++mf) {
            const int pooled_o = blk_m * 32 + mf * 16 + wv * 4 + q;
            #pragma unroll
            for (int nt = 0; nt < NT; ++nt) {
                const int oc = oc0 + nt * 16 + nloc;
                float mx = fmaxf(1.f + acc[mf][nt][0], 0.f);
                mx = fmaxf(mx, fmaxf(1.f + acc[mf][nt][1], 0.f));
                mx = fmaxf(mx, fmaxf(1.f + acc[mf][nt][2], 0.f));
                mx = fmaxf(mx, fmaxf(1.f + acc[mf][nt][3], 0.f));
                float s1 = 0.f;
                if (oc < COUT) {
                    outf[(size_t)pooled_o * COUT + oc] = mx;
                    s1 = mx;
                }
                float s2 = s1 * s1;
                s1 += __shfl_xor(s1, 16);
                s1 += __shfl_xor(s1, 32);
                s2 += __shfl_xor(s2, 16);
                s2 += __shfl_xor(s2, 32);
                if (q == 0) {
                    atomicAdd(&bs[nt * 16 + nloc], s1);
                    atomicAdd(&bs[NBLK + nt * 16 + nloc], s2);
                }
            }
        }
        __syncthreads();
        float* rowp = bnp + (size_t)(blk_m & 63) * 768;
        for (int i = tid; i < NBLK; i += 256) {
            const int oc = oc0 + i;
            if (oc < COUT) {
                atomicAdd(&rowp[oc], bs[i]);
                atomicAdd(&rowp[384 + oc], bs[NBLK + i]);
            }
        }
    } else {
        #pragma unroll
        for (int mf = 0; mf < 2; ++mf) {
            #pragma unroll
            for (int nt = 0; nt < NT; ++nt) {
                const int oc = oc0 + nt * 16 + nloc;
                #pragma unroll
                for (int r = 0; r < 4; ++r) {
                    const int mm = blk_m * 128 + mf * 64 + wv * 16 + q * 4 + r;
                    part[((size_t)kc * MTOT + mm) * COUT + oc] = acc[mf][nt][r];
                }
            }
        }
    }
}

// ================= split-K reduce + clamp + pool + fused BN stats =================
template<int COUT, int HP, int WP, int SPLIT>
__global__ __launch_bounds__(256) void pool_epi(const float* __restrict__ part,
                                                float* __restrict__ outf,
                                                float* __restrict__ bnp)
{
    constexpr int PO = 2 * 16 * HP * WP;
    constexpr int M = PO * 4;
    __shared__ float bs[2 * COUT];
    const int tid = threadIdx.x;
    for (int i = tid; i < 2 * COUT; i += 256) bs[i] = 0.f;
    __syncthreads();
    const int idx = blockIdx.x * 256 + tid;
    if (idx < PO * COUT) {
        const int oc = idx % COUT;
        const int p = idx / COUT;
        float v[4] = {0.f, 0.f, 0.f, 0.f};
        for (int s = 0; s < SPLIT; ++s)
            #pragma unroll
            for (int r = 0; r < 4; ++r)
                v[r] += part[((size_t)s * M + p * 4 + r) * COUT + oc];
        float mx = fmaxf(1.f + v[0], 0.f);
        mx = fmaxf(mx, fmaxf(1.f + v[1], 0.f));
        mx = fmaxf(mx, fmaxf(1.f + v[2], 0.f));
        mx = fmaxf(mx, fmaxf(1.f + v[3], 0.f));
        outf[(size_t)p * COUT + oc] = mx;
        atomicAdd(&bs[oc], mx);
        atomicAdd(&bs[COUT + oc], mx * mx);
    }
    __syncthreads();
    float* rowp = bnp + (size_t)(blockIdx.x & 63) * 768;
    for (int i = tid; i < COUT; i += 256) {
        atomicAdd(&rowp[i], bs[i]);
        atomicAdd(&rowp[384 + i], bs[COUT + i]);
    }
}

// ================= BN apply (st computed per-block from bnp region) -> bf16 halo interior =================
template<int C, int HP, int WP>
__global__ __launch_bounds__(256) void bn_apply_halo(const float* __restrict__ pre,
                                                     const float* __restrict__ bnp_l,
                                                     const float* __restrict__ gamma,
                                                     const float* __restrict__ beta,
                                                     float inv_n,
                                                     unsigned short* __restrict__ outh)
{
    __shared__ float st[2 * C];
    const int tid = threadIdx.x;
    for (int t = tid; t < 2 * C; t += 256) {
        const int kind = (t >= C) ? 1 : 0;
        const int c = t - kind * C;
        float s = 0.f;
        #pragma unroll 4
        for (int r = 0; r < 64; ++r) s += bnp_l[(size_t)r * 768 + kind * 384 + c];
        st[t] = s;
    }
    __syncthreads();
    for (int c = tid; c < C; c += 256) {
        const float mean = st[c] * inv_n;
        const float var  = st[C + c] * inv_n - mean * mean;
        const float sc   = gamma[c] * rsqrtf(var + EPS_BN);
        const float sh   = fmaf(-mean, sc, beta[c]);
        st[c] = sc; st[C + c] = sh;
    }
    __syncthreads();
    constexpr int PO = 2 * 16 * HP * WP;
    for (int idx = blockIdx.x * 256 + tid; idx < PO * C; idx += gridDim.x * 256) {
        const int c = idx % C;
        const int p = idx / C;
        const int pw = p % WP;
        const int ph = (p / WP) % HP;
        const int d  = (p / (WP * HP)) & 15;
        const int b  = p / (WP * HP * 16);
        const float v = fmaf(pre[idx], st[c], st[C + c]);
        outh[((((size_t)b * 18 + d + 1) * (HP + 2) + ph + 1) * (WP + 2) + pw + 1) * C + c] = f2bf(v);
    }
}

// ================= L5: flat pre-BN fp32 + per-block BN -> NCDHW flat fp32 for fc1 =================
__global__ __launch_bounds__(256) void transpose5_bn(const float* __restrict__ out5,
                                                     const float* __restrict__ bnp_l,
                                                     const float* __restrict__ gamma,
                                                     const float* __restrict__ beta,
                                                     float* __restrict__ h)
{
    __shared__ float st[768];
    const int tid = threadIdx.x;
    for (int t = tid; t < 768; t += 256) {
        const int kind = (t >= 384) ? 1 : 0;
        const int c = t - kind * 384;
        float s = 0.f;
        #pragma unroll 4
        for (int r = 0; r < 64; ++r) s += bnp_l[(size_t)r * 768 + kind * 384 + c];
        st[t] = s;
    }
    __syncthreads();
    const float inv_n = 1.f / 288.f;
    for (int c = tid; c < 384; c += 256) {
        const float mean = st[c] * inv_n;
        const float var  = st[384 + c] * inv_n - mean * mean;
        const float sc   = gamma[c] * rsqrtf(var + EPS_BN);
        const float sh   = fmaf(-mean, sc, beta[c]);
        st[c] = sc; st[384 + c] = sh;
    }
    __syncthreads();
    for (int idx = blockIdx.x * 256 + tid; idx < 110592; idx += gridDim.x * 256) {
        const int c = idx % 384;
        const int p = idx / 384;
        const int b = p / 144;
        const int sp = p % 144;
        h[(size_t)b * 55296 + c * 144 + sp] = fmaf(out5[idx], st[c], st[384 + c]);
    }
}

// ================= fc layers =================
__global__ __launch_bounds__(256) void fc1_k(const float* __restrict__ h,
                                             const float* __restrict__ w1,
                                             const float* __restrict__ b1,
                                             float* __restrict__ hout)
{
    __shared__ float r0[256];
    __shared__ float r1[256];
    const int j = blockIdx.x, tid = threadIdx.x;
    const float* wr = w1 + (size_t)j * 55296;
    float a0 = 0.f, a1 = 0.f;
    for (int k = tid * 4; k < 55296; k += 1024) {
        const float4 w = *(const float4*)(wr + k);
        const float4 u = *(const float4*)(h + k);
        const float4 v = *(const float4*)(h + 55296 + k);
        a0 += w.x * u.x + w.y * u.y + w.z * u.z + w.w * u.w;
        a1 += w.x * v.x + w.y * v.y + w.z * v.z + w.w * v.w;
    }
    r0[tid] = a0; r1[tid] = a1;
    __syncthreads();
    for (int off = 128; off > 0; off >>= 1) {
        if (tid < off) { r0[tid] += r0[tid + off]; r1[tid] += r1[tid + off]; }
        __syncthreads();
    }
    if (tid == 0) {
        hout[j]       = fmaxf(r0[0] + b1[j], 0.f);
        hout[512 + j] = fmaxf(r1[0] + b1[j], 0.f);
    }
}

__global__ __launch_bounds__(256) void fc23_k(const float* __restrict__ h1,
                                              const float* __restrict__ w2,
                                              const float* __restrict__ b2,
                                              const float* __restrict__ w3,
                                              const float* __restrict__ b3,
                                              float* __restrict__ out)
{
    __shared__ float h1s[1024];
    __shared__ float h2[512];
    const int tid = threadIdx.x;
    for (int i = tid; i < 1024; i += 256) h1s[i] = h1[i];
    __syncthreads();
    {
        const float* wr = w2 + (size_t)tid * 512;
        #pragma unroll
        for (int b = 0; b < 2; ++b) {
            float a = 0.f;
            const float* hh = h1s + b * 512;
            for (int k = 0; k < 512; ++k) a = fmaf(wr[k], hh[k], a);
            h2[b * 256 + tid] = fmaxf(a + b2[tid], 0.f);
        }
    }
    __syncthreads();
    if (tid < 101) {
        const float* wr = w3 + (size_t)tid * 256;
        #pragma unroll
        for (int b = 0; b < 2; ++b) {
            float a = 0.f;
            const float* hh = h2 + b * 256;
            for (int k = 0; k < 256; ++k) a = fmaf(wr[k], hh[k], a);
            out[b * 101 + tid] = a + b3[tid];
        }
    }
}

// ================= host =================
extern "C" void kernel_launch(void* const* d_in, const int* in_sizes, int n_in,
                              void* d_out, int out_size, void* d_ws, size_t ws_size,
                              hipStream_t stream)
{
    const float* x  = (const float*)d_in[0];
    const float* p[5], *al[5], *g[5], *q[5];
    for (int i = 0; i < 5; ++i) {
        p[i]  = (const float*)d_in[1 + 4 * i];
        al[i] = (const float*)d_in[2 + 4 * i];
        g[i]  = (const float*)d_in[3 + 4 * i];
        q[i]  = (const float*)d_in[4 + 4 * i];
    }
    const float* w1 = (const float*)d_in[21];
    const float* b1 = (const float*)d_in[22];
    const float* w2 = (const float*)d_in[23];
    const float* b2 = (const float*)d_in[24];
    const float* w3 = (const float*)d_in[25];
    const float* b3 = (const float*)d_in[26];

    float* ws = nullptr;
    hipGetSymbolAddress((void**)&ws, HIP_SYMBOL(g_ws));
    unsigned short* act = nullptr;
    hipGetSymbolAddress((void**)&act, HIP_SYMBOL(g_act));
    unsigned short* wb = nullptr;
    hipGetSymbolAddress((void**)&wb, HIP_SYMBOL(g_wb));

    float* part = ws + PART_OFF;
    float* pre  = ws + PRE_OFF;
    float* out5 = ws + OUT5_OFF;
    float* h    = ws + H_OFF;
    float* bnp  = ws + BNP_OFF;       // 5 regions x 49152
    float* h1   = ws + H1_OFF;
    // fuse-phase scratch (dead before convs): tbuf 22.15MB at ws+0, Wlin 5.3MB after
    unsigned short* tbuf = (unsigned short*)ws;
    unsigned short* wlin = tbuf + (size_t)2 * 10816 * 512;   // 11,075,584 ushorts

    unsigned short* xin = act + XIN_OFF;
    unsigned short* a1  = act + A1_OFF;
    unsigned short* a2  = act + A2_OFF;
    unsigned short* a3  = act + A3_OFF;
    unsigned short* a4  = act + A4_OFF;

    static const int KF[5] = {81, 648, 1296, 2592, 5184};
    static const int CO[5] = {24, 48, 96, 192, 384};
    static const int CP[5] = {4, 24, 48, 96, 192};
    static const int KP[5] = {128, 672, 1312, 2592, 5184};
    static const int APAD[5] = {64, 64, 128, 192, 384};          // alphaT padded rows
    static const int PPAD[5] = {128, 704, 1344, 2624, 5184};     // projT padded rows (KT*64)
    static const int KT[5] = {2, 11, 21, 41, 81};                // k-tiles
    static const int OT[5] = {1, 1, 2, 3, 6};                    // o-tiles (64-wide)
    static const int NOFT[5] = {2, 3, 6, 12, 24};                // o-frags = ceil(CO/16)
    static const int NPAD[5] = {32, 48, 96, 192, 384};           // Wlin rows (noft*16)

    // ---- merged init + prep (one dispatch) ----
    InitPrepArgs ip;
    Fuse3Args f3;
    ReordBArgs rb;
    int prepBlocks = 0;
    {
        int row = 0, blk = 0;
        ip.start[0] = 0;
        for (int i = 0; i < 5; ++i) {
            ip.src[i] = al[i]; ip.W[i] = CO[i]; ip.dstrow[i] = row;
            f3.aoff[i] = row;
            row += APAD[i];
            blk += (APAD[i] / 64) * 16;
            ip.start[i + 1] = blk;
        }
        for (int i = 0; i < 5; ++i) {
            ip.src[5 + i] = p[i]; ip.W[5 + i] = KF[i]; ip.dstrow[5 + i] = row;
            f3.poff[i] = row;
            row += PPAD[i];
            blk += (PPAD[i] / 64) * 16;
            ip.start[5 + i + 1] = blk;
        }
        ip.rowtot = row;   // 10816
        f3.rowtot = row;
        prepBlocks = blk;  // 2704
        ip.prepBlocks = prepBlocks;
        ip.x = x; ip.xp = xin; ip.bnp = bnp;
        ip.zp = (int4*)(act + A1_OFF);
        ip.nz = (int)((AR_TOT - A1_OFF) * 2 / 16);
        ip.wbz = (int4*)wb;
        ip.nwb = (int)(WB_TOT * 2 / 16);
        const int initBlocks = (1871424 + 255) / 256;   // 7311
        init_prep<<<prepBlocks + initBlocks, 256, 0, stream>>>(ip, tbuf);
    }

    // ---- fuse GEMM (split-bf16 3-pass, LDS-staged 2-phase) -> bf16 Wlin ----
    {
        int s0 = 0, woff = 0;
        for (int i = 0; i < 5; ++i) {
            f3.woff[i] = woff;
            f3.KL[i] = KT[i] * 64;
            f3.noft[i] = NOFT[i];
            f3.kt[i] = KT[i];
            f3.start[i] = s0;
            s0 += OT[i] * KT[i];
            woff += NPAD[i] * KT[i] * 64;
        }
        f3.start[5] = s0;   // 664 blocks
        fuse_mfma<<<s0, 256, 0, stream>>>(tbuf, wlin, f3);
    }

    // ---- reorder: Wlin -> Wb (coalesced row writes) ----
    {
        int s0 = 0, woff = 0;
        for (int i = 0; i < 5; ++i) {
            rb.woff[i] = woff;
            rb.wboff[i] = (int)WB_OFF[i];
            rb.K[i] = KF[i]; rb.KL[i] = KT[i] * 64; rb.KP[i] = KP[i]; rb.CP[i] = CP[i];
            rb.start[i] = s0;
            s0 += CO[i];
            woff += NPAD[i] * KT[i] * 64;
        }
        rb.start[5] = s0;
        reorder_b<<<s0, 256, 0, stream>>>(wlin, wb, rb);
    }

    // ---- L1 ----  M=401408 -> 3136 blocks of 128 rows
    conv_mfma<4, 24, 128, 112, 112, 56, 56, 32, 1>
        <<<dim3(3136, 1), 256, 0, stream>>>(xin, wb + WB_OFF[0], pre, nullptr, bnp);
    bn_apply_halo<24, 56, 56><<<1024, 256, 0, stream>>>(pre, bnp, g[0], q[0], 1.f / 100352.f, a1);

    // ---- L2 ----  M=100352 -> 784
    conv_mfma<24, 48, 672, 56, 56, 28, 28, 48, 1>
        <<<dim3(784, 1), 256, 0, stream>>>(a1, wb + WB_OFF[1], pre, nullptr, bnp + 49152);
    bn_apply_halo<48, 28, 28><<<1024, 256, 0, stream>>>(pre, bnp + 49152, g[1], q[1], 1.f / 25088.f, a2);

    // ---- L3 ----  M=25088 -> 196
    conv_mfma<48, 96, 1312, 28, 28, 14, 14, 48, 1>
        <<<dim3(196, 2), 256, 0, stream>>>(a2, wb + WB_OFF[2], pre, nullptr, bnp + 2 * 49152);
    bn_apply_halo<96, 14, 14><<<1024, 256, 0, stream>>>(pre, bnp + 2 * 49152, g[2], q[2], 1.f / 6272.f, a3);

    // ---- L4 (split-K 3) ----  M=6272 -> 49
    conv_mfma<96, 192, 2592, 14, 14, 7, 7, 64, 3>
        <<<dim3(49, 3, 3), 256, 0, stream>>>(a3, wb + WB_OFF[3], nullptr, part, nullptr);
    pool_epi<192, 7, 7, 3><<<1176, 256, 0, stream>>>(part, pre, bnp + 3 * 49152);
    bn_apply_halo<192, 7, 7><<<1024, 256, 0, stream>>>(pre, bnp + 3 * 49152, g[3], q[3], 1.f / 1568.f, a4);

    // ---- L5 (split-K 6) ----  M=1152 -> 9
    conv_mfma<192, 384, 5184, 7, 7, 3, 3, 64, 6>
        <<<dim3(9, 6, 6), 256, 0, stream>>>(a4, wb + WB_OFF[4], nullptr, part, nullptr);
    pool_epi<384, 3, 3, 6><<<432, 256, 0, stream>>>(part, out5, bnp + 4 * 49152);

    // ---- head ----
    transpose5_bn<<<432, 256, 0, stream>>>(out5, bnp + 4 * 49152, g[4], q[4], h);
    fc1_k<<<512, 256, 0, stream>>>(h, w1, b1, h1);
    fc23_k<<<1, 256, 0, stream>>>(h1, w2, b2, w3, b3, (float*)d_out);
}

// Round 10
// 496.435 us; speedup vs baseline: 1.0539x; 1.0539x over previous
//
#include <hip/hip_runtime.h>

#define EPS_BN 1e-5f

typedef __attribute__((ext_vector_type(8))) short sh8;
typedef __attribute__((ext_vector_type(4))) short sh4;
typedef __attribute__((ext_vector_type(4))) float f32x4;

// ================= fp32 workspace arena =================
// [0, ~27.5MB): bf16 hi/lo alphaT/projT scratch (tbuf) + bf16 Wlin — dead before convs run.
static const size_t PART_OFF = 2645784;   // split-K partials (conv L4/L5 phase)
static const size_t PRE_OFF  = 6258456;   // pre-BN flat conv output (max 2408448)
static const size_t OUT5_OFF = 8666904;   // 110592 L5 pre-BN flat
static const size_t H_OFF    = 8777496;   // 110592 fc1 input (NCDHW flat)
static const size_t BNP_OFF  = 8888088;   // 5 regions x (64 rows x 768) = 245760 bn partials
static const size_t H1_OFF   = 9133848;   // 1024 fc1 output
static const size_t ST_OFF   = 9134872;   // 768 per-channel scale/shift
static const size_t WS_TOT   = 9135640;   // ~36.5 MB
__device__ __align__(256) float g_ws[WS_TOT];

// bf16 activation arena (halo-padded NDHWC)
static const size_t XIN_OFF = 0;         // [2][18][114][114][4]  = 1871424
static const size_t A1_OFF  = 1871424;   // [2][18][58][58][24]   = 2905344
static const size_t A2_OFF  = 4776768;   // [2][18][30][30][48]   = 1555200
static const size_t A3_OFF  = 6331968;   // [2][18][16][16][96]   = 884736
static const size_t A4_OFF  = 7216704;   // [2][18][9][9][192]    = 559872
static const size_t AR_TOT  = 7776576;
__device__ __align__(256) unsigned short g_act[AR_TOT];

// bf16 conv weights [NPAD][KPAD], k-order = s*CPAD+c
static const size_t WB_OFF[5] = {0, 4096, 36352, 162304, 659968};
static const size_t WB_TOT    = 2650624;
__device__ __align__(256) unsigned short g_wb[WB_TOT];

__device__ inline unsigned short f2bf(float v) {
    unsigned u = __float_as_uint(v);
    return (unsigned short)((u + 0x7fffu + ((u >> 16) & 1u)) >> 16);
}
__device__ inline float bf2f(unsigned short h) {
    return __uint_as_float(((unsigned)h) << 16);
}

// ================= merged init (convert+zero) + prep (transpose/split-convert) =================
struct InitPrepArgs {
    const float* src[10];
    int W[10];
    int dstrow[10];
    int start[11];
    int rowtot;          // lo-plane row offset
    int prepBlocks;
    const float* x;
    unsigned short* xp;
    float* bnp;          // 245760 floats (5 regions)
    int4* zp; int nz;
    int4* wbz; int nwb;
};

__global__ __launch_bounds__(256) void init_prep(InitPrepArgs a, unsigned short* __restrict__ dst)
{
    __shared__ unsigned short tileh[32 * 72];
    __shared__ unsigned short tilel[32 * 72];
    const int tid = threadIdx.x;

    if (blockIdx.x >= a.prepBlocks) {
        // ---- init path ----
        const int i = (blockIdx.x - a.prepBlocks) * 256 + tid;
        if (i < a.nz) a.zp[i] = make_int4(0, 0, 0, 0);
        if (i < a.nwb) a.wbz[i] = make_int4(0, 0, 0, 0);
        if (i < 245760) a.bnp[i] = 0.f;
        if (i >= 1871424) return;
        const int c = i & 3;
        int t = i >> 2;
        const int xx = t % 114; t /= 114;
        const int yy = t % 114; t /= 114;
        const int zz = t % 18;
        const int b  = t / 18;
        float v = 0.f;
        if (c < 3 && (unsigned)(zz - 1) < 16u && (unsigned)(yy - 1) < 112u && (unsigned)(xx - 1) < 112u)
            v = a.x[(((size_t)b * 3 + c) * 16 + (zz - 1)) * 12544 + (yy - 1) * 112 + (xx - 1)];
        a.xp[i] = f2bf(v);
        return;
    }

    // ---- prep path ----
    int m = 0;
    {
        const int bx = blockIdx.x;
        while (m < 9 && bx >= a.start[m + 1]) ++m;
    }
    const int t  = blockIdx.x - a.start[m];
    const int tw = t >> 4, tp = t & 15;
    const int p0 = tp * 32, w0 = tw * 64;
    const int W = a.W[m];
    const float* __restrict__ src = a.src[m];

    #pragma unroll
    for (int e = 0; e < 8; ++e) {
        const int idx = tid + e * 256;        // 0..2047
        const int w = idx & 63, pr = idx >> 6;
        const int gw = w0 + w;
        float v = 0.f;
        if (gw < W) v = src[(size_t)(p0 + pr) * W + gw];
        const unsigned short hh = f2bf(v);
        tileh[pr * 72 + w] = hh;
        tilel[pr * 72 + w] = f2bf(v - bf2f(hh));
    }
    __syncthreads();
    {
        const int wr = tid >> 2, pg = (tid & 3) * 8;
        sh8 packh, packl;
        #pragma unroll
        for (int e = 0; e < 8; ++e) {
            packh[e] = (short)tileh[(pg + e) * 72 + wr];
            packl[e] = (short)tilel[(pg + e) * 72 + wr];
        }
        const size_t rh = (size_t)a.dstrow[m] + w0 + wr;
        *(sh8*)&dst[rh * 512 + p0 + pg] = packh;
        *(sh8*)&dst[(rh + a.rowtot) * 512 + p0 + pg] = packl;
    }
}

// ================= MFMA fuse v3: LDS-staged, 2-phase, (o-tile x k-tile) grid =================
struct Fuse3Args {
    int aoff[5], poff[5];    // hi-plane row offsets into tbuf
    int woff[5];             // ushort offset into Wlin (rows = NPAD)
    int KL[5];               // linear padded K (= KT*64)
    int noft[5];             // total o-frags = ceil(CO/16)
    int kt[5];               // k-tiles per layer
    int start[6];            // block prefix = cumsum(OT*KT)
    int rowtot;              // lo-plane row offset
};

__global__ __launch_bounds__(256) void fuse_mfma(const unsigned short* __restrict__ tb,
                                                 unsigned short* __restrict__ wlin,
                                                 Fuse3Args a)
{
    __shared__ __align__(16) unsigned short Ah[2][64 * 40];
    __shared__ __align__(16) unsigned short Al[2][64 * 40];
    __shared__ __align__(16) unsigned short Bh[2][64 * 40];
    __shared__ __align__(16) unsigned short Bl[2][64 * 40];

    int l = 0;
    {
        const int bx = blockIdx.x;
        while (l < 4 && bx >= a.start[l + 1]) ++l;
    }
    const int idx = blockIdx.x - a.start[l];
    const int ot = idx / a.kt[l];
    const int kt = idx % a.kt[l];
    const int tid = threadIdx.x;
    const int lane = tid & 63;
    const int wv = tid >> 6;
    const size_t LOFF = (size_t)a.rowtot * 512;

    const int srow = tid >> 2, spg = (tid & 3) * 8;
    const unsigned short* asrc = tb + ((size_t)(a.aoff[l] + ot * 64 + srow)) * 512 + spg;
    const unsigned short* bsrc = tb + ((size_t)(a.poff[l] + kt * 64 + srow)) * 512 + spg;
    const int sidx = srow * 40 + spg;

    f32x4 acc[4];
    #pragma unroll
    for (int i = 0; i < 4; ++i) acc[i] = (f32x4){0.f, 0.f, 0.f, 0.f};

    sh8 rah, ral, rbh, rbl;

    rah = *(const sh8*)(asrc);
    ral = *(const sh8*)(asrc + LOFF);
    rbh = *(const sh8*)(bsrc);
    rbl = *(const sh8*)(bsrc + LOFF);
    *(sh8*)&Ah[0][sidx] = rah;
    *(sh8*)&Al[0][sidx] = ral;
    *(sh8*)&Bh[0][sidx] = rbh;
    *(sh8*)&Bl[0][sidx] = rbl;
    __syncthreads();

    const int fr = (wv * 16 + (lane & 15)) * 40 + (lane >> 4) * 8;
    int cur = 0;
    for (int s = 0; s < 16; ++s) {
        if (s + 1 < 16) {
            const int pn = (s + 1) * 32;
            rah = *(const sh8*)(asrc + pn);
            ral = *(const sh8*)(asrc + LOFF + pn);
            rbh = *(const sh8*)(bsrc + pn);
            rbl = *(const sh8*)(bsrc + LOFF + pn);
        }
        const sh8 ah  = *(const sh8*)&Ah[cur][fr];
        const sh8 alo = *(const sh8*)&Al[cur][fr];
        #pragma unroll
        for (int nt = 0; nt < 4; ++nt) {
            const int bidx = (nt * 16 + (lane & 15)) * 40 + (lane >> 4) * 8;
            const sh8 bh = *(const sh8*)&Bh[cur][bidx];
            const sh8 bl = *(const sh8*)&Bl[cur][bidx];
            acc[nt] = __builtin_amdgcn_mfma_f32_16x16x32_bf16(ah, bh, acc[nt], 0, 0, 0);
            acc[nt] = __builtin_amdgcn_mfma_f32_16x16x32_bf16(ah, bl, acc[nt], 0, 0, 0);
            acc[nt] = __builtin_amdgcn_mfma_f32_16x16x32_bf16(alo, bh, acc[nt], 0, 0, 0);
        }
        if (s + 1 < 16) {
            *(sh8*)&Ah[cur ^ 1][sidx] = rah;
            *(sh8*)&Al[cur ^ 1][sidx] = ral;
            *(sh8*)&Bh[cur ^ 1][sidx] = rbh;
            *(sh8*)&Bl[cur ^ 1][sidx] = rbl;
        }
        __syncthreads();
        cur ^= 1;
    }

    const int f = ot * 4 + wv;
    if (f < a.noft[l]) {
        const int KL = a.KL[l];
        unsigned short* wrow = wlin + a.woff[l];
        #pragma unroll
        for (int nt = 0; nt < 4; ++nt) {
            const int k = kt * 64 + nt * 16 + (lane & 15);
            #pragma unroll
            for (int j = 0; j < 4; ++j) {
                const int o = f * 16 + (lane >> 4) * 4 + j;
                wrow[(size_t)o * KL + k] = f2bf(acc[nt][j]);
            }
        }
    }
}

// ================= reorder: Wlin[o][k] -> Wb[o][s*CPAD+c], coalesced row writes via LDS =================
struct ReordBArgs {
    int woff[5], wboff[5];
    int K[5], KL[5], KP[5], CP[5];
    int start[6];     // prefix over CO
};

__global__ __launch_bounds__(256) void reorder_b(const unsigned short* __restrict__ wlin,
                                                 unsigned short* __restrict__ wb,
                                                 ReordBArgs a)
{
    __shared__ __align__(16) unsigned short lds[5184];
    int l = 0;
    {
        const int bx = blockIdx.x;
        while (l < 4 && bx >= a.start[l + 1]) ++l;
    }
    const int o = blockIdx.x - a.start[l];
    const int K = a.K[l], KL = a.KL[l], KP = a.KP[l], CP = a.CP[l];
    const int tid = threadIdx.x;
    for (int i = tid; i < KP; i += 256) lds[i] = 0;
    __syncthreads();
    const unsigned short* src = wlin + a.woff[l] + (size_t)o * KL;
    for (int k = tid; k < K; k += 256) {
        const int c = k / 27, s = k - c * 27;
        lds[s * CP + c] = src[k];
    }
    __syncthreads();
    unsigned short* drow = wb + a.wboff[l] + (size_t)o * KP;
    for (int i = tid * 8; i < KP; i += 2048)
        *(sh8*)&drow[i] = *(const sh8*)&lds[i];
}

// ================= implicit-GEMM MFMA conv + clamp(1+x,0) + pool(1,2,2) + fused BN stats =================
// 128-row M-tile, 2-phase pipeline, one barrier per 32-k step. bnp is the per-layer region.
template<int CPAD, int COUT, int KPAD, int HI, int WI, int HP, int WP, int NBLK, int SPLIT>
__global__ __launch_bounds__(256) void conv_mfma(
    const unsigned short* __restrict__ in, const unsigned short* __restrict__ Wb,
    float* __restrict__ outf, float* __restrict__ part, float* __restrict__ bnp)
{
    constexpr int NT = NBLK / 16;
    constexpr int HI2 = HI + 2, WI2 = WI + 2;
    constexpr bool C8 = (CPAD % 8 == 0);
    constexpr int TABN = C8 ? KPAD / 8 : KPAD / 4;
    constexpr int NSTEP = KPAD / 32 / SPLIT;
    constexpr int MTOT = 2 * 16 * HP * WP * 4;
    constexpr bool BONCE = (NBLK * KPAD * 2 <= 16384);   // L1 only
    constexpr int BROW = BONCE ? (KPAD + 8) : 40;        // B row stride (shorts)
    constexpr int BS_ELEMS = BONCE ? NBLK * BROW : 2 * NBLK * 40;

    __shared__ __align__(16) unsigned short As[2][128 * 40];
    __shared__ __align__(16) unsigned short Bs[BS_ELEMS];
    __shared__ int tab[TABN];
    __shared__ float bs[(SPLIT == 1) ? 2 * NBLK : 1];

    const int tid = threadIdx.x;
    const int lane = tid & 63;
    const int wv = tid >> 6;
    const int blk_m = blockIdx.x;
    const int oc0 = blockIdx.y * NBLK;
    const int kc = (SPLIT > 1) ? blockIdx.z : 0;

    for (int i = tid; i < TABN; i += 256) {
        const int k = i * (C8 ? 8 : 4);
        const int s = k / CPAD, c = k % CPAD;
        tab[i] = (s < 27) ? ((((s / 9) * HI2 + (s % 9) / 3) * WI2 + (s % 3)) * CPAD + c) : -1;
    }

    if constexpr (BONCE) {
        for (int i = tid; i < NBLK * KPAD / 8; i += 256) {
            const int r = i / (KPAD / 8), kk = i - r * (KPAD / 8);
            *(sh8*)&Bs[r * BROW + kk * 8] = *(const sh8*)&Wb[(size_t)(oc0 + r) * KPAD + kk * 8];
        }
    }

    // A-staging mapping: thread stages row srow = tid>>1, half = tid&1
    const int srow = tid >> 1;
    const int half = tid & 1;
    const int m_g = blk_m * 128 + srow;
    const int pooled_s = m_g >> 2, sub_s = m_g & 3;
    const int pw_g = pooled_s % WP;
    const int ph_g = (pooled_s / WP) % HP;
    const int d_g  = (pooled_s / (WP * HP)) & 15;
    const int b_g  = pooled_s / (WP * HP * 16);
    const int h_g = 2 * ph_g + (sub_s >> 1);
    const int w_g = 2 * pw_g + (sub_s & 1);
    const size_t base_m = ((((size_t)b_g * 18 + d_g) * HI2 + h_g) * WI2 + w_g) * CPAD;

    const int brow = tid >> 2, bcc = tid & 3;
    const bool bload = (tid < NBLK * 4);

    f32x4 acc[2][NT];
    #pragma unroll
    for (int mf = 0; mf < 2; ++mf)
        #pragma unroll
        for (int i = 0; i < NT; ++i) acc[mf][i] = (f32x4){0.f, 0.f, 0.f, 0.f};

    const int k_begin = kc * NSTEP * 32;

    sh8 aA0, aA1;
    sh4 aP0, aP1, aP2, aP3;
    sh8 brg;

    __syncthreads();  // tab (and BONCE B) visible

    {
        const int k0 = k_begin;
        if constexpr (C8) {
            const int o0 = tab[(k0 >> 3) + half * 2];
            const int o1 = tab[(k0 >> 3) + half * 2 + 1];
            aA0 = (sh8){0, 0, 0, 0, 0, 0, 0, 0};
            aA1 = (sh8){0, 0, 0, 0, 0, 0, 0, 0};
            if (o0 >= 0) aA0 = *(const sh8*)(in + base_m + o0);
            if (o1 >= 0) aA1 = *(const sh8*)(in + base_m + o1);
            *(sh8*)&As[0][srow * 40 + (half * 2) * 8]     = aA0;
            *(sh8*)&As[0][srow * 40 + (half * 2 + 1) * 8] = aA1;
        } else {
            const int t0 = tab[(k0 >> 2) + half * 4];
            const int t1 = tab[(k0 >> 2) + half * 4 + 1];
            const int t2 = tab[(k0 >> 2) + half * 4 + 2];
            const int t3 = tab[(k0 >> 2) + half * 4 + 3];
            aP0 = (sh4){0, 0, 0, 0}; aP1 = (sh4){0, 0, 0, 0};
            aP2 = (sh4){0, 0, 0, 0}; aP3 = (sh4){0, 0, 0, 0};
            if (t0 >= 0) aP0 = *(const sh4*)(in + base_m + t0);
            if (t1 >= 0) aP1 = *(const sh4*)(in + base_m + t1);
            if (t2 >= 0) aP2 = *(const sh4*)(in + base_m + t2);
            if (t3 >= 0) aP3 = *(const sh4*)(in + base_m + t3);
            *(sh4*)&As[0][srow * 40 + (half * 4) * 4]     = aP0;
            *(sh4*)&As[0][srow * 40 + (half * 4 + 1) * 4] = aP1;
            *(sh4*)&As[0][srow * 40 + (half * 4 + 2) * 4] = aP2;
            *(sh4*)&As[0][srow * 40 + (half * 4 + 3) * 4] = aP3;
        }
        if constexpr (!BONCE) {
            if (bload) {
                brg = *(const sh8*)&Wb[(size_t)(oc0 + brow) * KPAD + k0 + bcc * 8];
                *(sh8*)&Bs[0 + brow * 40 + bcc * 8] = brg;
            }
        }
    }
    __syncthreads();

    int cur = 0;
    for (int s = 0; s < NSTEP; ++s) {
        const int k0 = k_begin + s * 32;
        if (s + 1 < NSTEP) {
            const int kn = k0 + 32;
            if constexpr (C8) {
                const int o0 = tab[(kn >> 3) + half * 2];
                const int o1 = tab[(kn >> 3) + half * 2 + 1];
                aA0 = (sh8){0, 0, 0, 0, 0, 0, 0, 0};
                aA1 = (sh8){0, 0, 0, 0, 0, 0, 0, 0};
                if (o0 >= 0) aA0 = *(const sh8*)(in + base_m + o0);
                if (o1 >= 0) aA1 = *(const sh8*)(in + base_m + o1);
            } else {
                const int t0 = tab[(kn >> 2) + half * 4];
                const int t1 = tab[(kn >> 2) + half * 4 + 1];
                const int t2 = tab[(kn >> 2) + half * 4 + 2];
                const int t3 = tab[(kn >> 2) + half * 4 + 3];
                aP0 = (sh4){0, 0, 0, 0}; aP1 = (sh4){0, 0, 0, 0};
                aP2 = (sh4){0, 0, 0, 0}; aP3 = (sh4){0, 0, 0, 0};
                if (t0 >= 0) aP0 = *(const sh4*)(in + base_m + t0);
                if (t1 >= 0) aP1 = *(const sh4*)(in + base_m + t1);
                if (t2 >= 0) aP2 = *(const sh4*)(in + base_m + t2);
                if (t3 >= 0) aP3 = *(const sh4*)(in + base_m + t3);
            }
            if constexpr (!BONCE) {
                if (bload) brg = *(const sh8*)&Wb[(size_t)(oc0 + brow) * KPAD + kn + bcc * 8];
            }
        }
        const sh8 af0 = *(const sh8*)&As[cur][(wv * 16 + (lane & 15)) * 40 + (lane >> 4) * 8];
        const sh8 af1 = *(const sh8*)&As[cur][(64 + wv * 16 + (lane & 15)) * 40 + (lane >> 4) * 8];
        #pragma unroll
        for (int nt = 0; nt < NT; ++nt) {
            sh8 bf;
            if constexpr (BONCE)
                bf = *(const sh8*)&Bs[(nt * 16 + (lane & 15)) * BROW + k0 + (lane >> 4) * 8];
            else
                bf = *(const sh8*)&Bs[cur * NBLK * 40 + (nt * 16 + (lane & 15)) * 40 + (lane >> 4) * 8];
            acc[0][nt] = __builtin_amdgcn_mfma_f32_16x16x32_bf16(af0, bf, acc[0][nt], 0, 0, 0);
            acc[1][nt] = __builtin_amdgcn_mfma_f32_16x16x32_bf16(af1, bf, acc[1][nt], 0, 0, 0);
        }
        if (s + 1 < NSTEP) {
            if constexpr (C8) {
                *(sh8*)&As[cur ^ 1][srow * 40 + (half * 2) * 8]     = aA0;
                *(sh8*)&As[cur ^ 1][srow * 40 + (half * 2 + 1) * 8] = aA1;
            } else {
                *(sh4*)&As[cur ^ 1][srow * 40 + (half * 4) * 4]     = aP0;
                *(sh4*)&As[cur ^ 1][srow * 40 + (half * 4 + 1) * 4] = aP1;
                *(sh4*)&As[cur ^ 1][srow * 40 + (half * 4 + 2) * 4] = aP2;
                *(sh4*)&As[cur ^ 1][srow * 40 + (half * 4 + 3) * 4] = aP3;
            }
            if constexpr (!BONCE) {
                if (bload) *(sh8*)&Bs[(cur ^ 1) * NBLK * 40 + brow * 40 + bcc * 8] = brg;
            }
        }
        __syncthreads();
        cur ^= 1;
    }

    const int q = lane >> 4;
    const int nloc = lane & 15;
    if constexpr (SPLIT == 1) {
        for (int i = tid; i < 2 * NBLK; i += 256) bs[i] = 0.f;
        __syncthreads();
        #pragma unroll
        for (int mf = 0; mf < 2; ++mf) {
            const int pooled_o = blk_m * 32 + mf * 16 + wv * 4 + q;
            #pragma unroll
            for (int nt = 0; nt < NT; ++nt) {
                const int oc = oc0 + nt * 16 + nloc;
                float mx = fmaxf(1.f + acc[mf][nt][0], 0.f);
                mx = fmaxf(mx, fmaxf(1.f + acc[mf][nt][1], 0.f));
                mx = fmaxf(mx, fmaxf(1.f + acc[mf][nt][2], 0.f));
                mx = fmaxf(mx, fmaxf(1.f + acc[mf][nt][3], 0.f));
                float s1 = 0.f;
                if (oc < COUT) {
                    outf[(size_t)pooled_o * COUT + oc] = mx;
                    s1 = mx;
                }
                float s2 = s1 * s1;
                s1 += __shfl_xor(s1, 16);
                s1 += __shfl_xor(s1, 32);
                s2 += __shfl_xor(s2, 16);
                s2 += __shfl_xor(s2, 32);
                if (q == 0) {
                    atomicAdd(&bs[nt * 16 + nloc], s1);
                    atomicAdd(&bs[NBLK + nt * 16 + nloc], s2);
                }
            }
        }
        __syncthreads();
        float* rowp = bnp + (size_t)(blk_m & 63) * 768;
        for (int i = tid; i < NBLK; i += 256) {
            const int oc = oc0 + i;
            if (oc < COUT) {
                atomicAdd(&rowp[oc], bs[i]);
                atomicAdd(&rowp[384 + oc], bs[NBLK + i]);
            }
        }
    } else {
        #pragma unroll
        for (int mf = 0; mf < 2; ++mf) {
            #pragma unroll
            for (int nt = 0; nt < NT; ++nt) {
                const int oc = oc0 + nt * 16 + nloc;
                #pragma unroll
                for (int r = 0; r < 4; ++r) {
                    const int mm = blk_m * 128 + mf * 64 + wv * 16 + q * 4 + r;
                    part[((size_t)kc * MTOT + mm) * COUT + oc] = acc[mf][nt][r];
                }
            }
        }
    }
}

// ================= split-K reduce + clamp + pool + fused BN stats =================
template<int COUT, int HP, int WP, int SPLIT>
__global__ __launch_bounds__(256) void pool_epi(const float* __restrict__ part,
                                                float* __restrict__ outf,
                                                float* __restrict__ bnp)
{
    constexpr int PO = 2 * 16 * HP * WP;
    constexpr int M = PO * 4;
    __shared__ float bs[2 * COUT];
    const int tid = threadIdx.x;
    for (int i = tid; i < 2 * COUT; i += 256) bs[i] = 0.f;
    __syncthreads();
    const int idx = blockIdx.x * 256 + tid;
    if (idx < PO * COUT) {
        const int oc = idx % COUT;
        const int p = idx / COUT;
        float v[4] = {0.f, 0.f, 0.f, 0.f};
        for (int s = 0; s < SPLIT; ++s)
            #pragma unroll
            for (int r = 0; r < 4; ++r)
                v[r] += part[((size_t)s * M + p * 4 + r) * COUT + oc];
        float mx = fmaxf(1.f + v[0], 0.f);
        mx = fmaxf(mx, fmaxf(1.f + v[1], 0.f));
        mx = fmaxf(mx, fmaxf(1.f + v[2], 0.f));
        mx = fmaxf(mx, fmaxf(1.f + v[3], 0.f));
        outf[(size_t)p * COUT + oc] = mx;
        atomicAdd(&bs[oc], mx);
        atomicAdd(&bs[COUT + oc], mx * mx);
    }
    __syncthreads();
    float* rowp = bnp + (size_t)(blockIdx.x & 63) * 768;
    for (int i = tid; i < COUT; i += 256) {
        atomicAdd(&rowp[i], bs[i]);
        atomicAdd(&rowp[384 + i], bs[COUT + i]);
    }
}

// ================= BN reduce: sum 64 bnp rows per channel, compute st (no re-zero needed) =================
__global__ __launch_bounds__(64) void bn_reduce(const float* __restrict__ bnp,
                                                const float* __restrict__ gamma,
                                                const float* __restrict__ beta,
                                                float* __restrict__ st,
                                                float inv_n)
{
    const int c = blockIdx.x, tid = threadIdx.x;
    float s = bnp[(size_t)tid * 768 + c];
    float q = bnp[(size_t)tid * 768 + 384 + c];
    #pragma unroll
    for (int off = 32; off > 0; off >>= 1) {
        s += __shfl_down(s, off);
        q += __shfl_down(q, off);
    }
    if (tid == 0) {
        const float mean = s * inv_n;
        const float var  = q * inv_n - mean * mean;
        const float sc   = gamma[c] * rsqrtf(var + EPS_BN);
        st[2 * c]     = sc;
        st[2 * c + 1] = fmaf(-mean, sc, beta[c]);
    }
}

// ================= BN apply: pre-BN fp32 flat -> bf16 halo interior =================
template<int C, int HP, int WP>
__global__ __launch_bounds__(256) void bn_apply_halo(const float* __restrict__ pre,
                                                     const float* __restrict__ st,
                                                     unsigned short* __restrict__ outh)
{
    constexpr int PO = 2 * 16 * HP * WP;
    const int idx = blockIdx.x * 256 + threadIdx.x;
    if (idx >= PO * C) return;
    const int c = idx % C;
    const int p = idx / C;
    const int pw = p % WP;
    const int ph = (p / WP) % HP;
    const int d  = (p / (WP * HP)) & 15;
    const int b  = p / (WP * HP * 16);
    const float v = fmaf(pre[idx], st[2 * c], st[2 * c + 1]);
    outh[((((size_t)b * 18 + d + 1) * (HP + 2) + ph + 1) * (WP + 2) + pw + 1) * C + c] = f2bf(v);
}

// ================= L5: flat pre-BN fp32 + BN -> NCDHW flat fp32 for fc1 =================
__global__ __launch_bounds__(256) void transpose5(const float* __restrict__ out5,
                                                  const float* __restrict__ st,
                                                  float* __restrict__ h)
{
    const int idx = blockIdx.x * 256 + threadIdx.x;
    if (idx >= 110592) return;
    const int c = idx % 384;
    const int p = idx / 384;
    const int b = p / 144;
    const int sp = p % 144;
    h[(size_t)b * 55296 + c * 144 + sp] = fmaf(out5[idx], st[2 * c], st[2 * c + 1]);
}

// ================= fc layers =================
__global__ __launch_bounds__(256) void fc1_k(const float* __restrict__ h,
                                             const float* __restrict__ w1,
                                             const float* __restrict__ b1,
                                             float* __restrict__ hout)
{
    __shared__ float r0[256];
    __shared__ float r1[256];
    const int j = blockIdx.x, tid = threadIdx.x;
    const float* wr = w1 + (size_t)j * 55296;
    float a0 = 0.f, a1 = 0.f;
    for (int k = tid * 4; k < 55296; k += 1024) {
        const float4 w = *(const float4*)(wr + k);
        const float4 u = *(const float4*)(h + k);
        const float4 v = *(const float4*)(h + 55296 + k);
        a0 += w.x * u.x + w.y * u.y + w.z * u.z + w.w * u.w;
        a1 += w.x * v.x + w.y * v.y + w.z * v.z + w.w * v.w;
    }
    r0[tid] = a0; r1[tid] = a1;
    __syncthreads();
    for (int off = 128; off > 0; off >>= 1) {
        if (tid < off) { r0[tid] += r0[tid + off]; r1[tid] += r1[tid + off]; }
        __syncthreads();
    }
    if (tid == 0) {
        hout[j]       = fmaxf(r0[0] + b1[j], 0.f);
        hout[512 + j] = fmaxf(r1[0] + b1[j], 0.f);
    }
}

__global__ __launch_bounds__(256) void fc23_k(const float* __restrict__ h1,
                                              const float* __restrict__ w2,
                                              const float* __restrict__ b2,
                                              const float* __restrict__ w3,
                                              const float* __restrict__ b3,
                                              float* __restrict__ out)
{
    __shared__ float h1s[1024];
    __shared__ float h2[512];
    const int tid = threadIdx.x;
    for (int i = tid; i < 1024; i += 256) h1s[i] = h1[i];
    __syncthreads();
    {
        const float* wr = w2 + (size_t)tid * 512;
        #pragma unroll
        for (int b = 0; b < 2; ++b) {
            float a = 0.f;
            const float* hh = h1s + b * 512;
            for (int k = 0; k < 512; ++k) a = fmaf(wr[k], hh[k], a);
            h2[b * 256 + tid] = fmaxf(a + b2[tid], 0.f);
        }
    }
    __syncthreads();
    if (tid < 101) {
        const float* wr = w3 + (size_t)tid * 256;
        #pragma unroll
        for (int b = 0; b < 2; ++b) {
            float a = 0.f;
            const float* hh = h2 + b * 256;
            for (int k = 0; k < 256; ++k) a = fmaf(wr[k], hh[k], a);
            out[b * 101 + tid] = a + b3[tid];
        }
    }
}

// ================= host =================
extern "C" void kernel_launch(void* const* d_in, const int* in_sizes, int n_in,
                              void* d_out, int out_size, void* d_ws, size_t ws_size,
                              hipStream_t stream)
{
    const float* x  = (const float*)d_in[0];
    const float* p[5], *al[5], *g[5], *q[5];
    for (int i = 0; i < 5; ++i) {
        p[i]  = (const float*)d_in[1 + 4 * i];
        al[i] = (const float*)d_in[2 + 4 * i];
        g[i]  = (const float*)d_in[3 + 4 * i];
        q[i]  = (const float*)d_in[4 + 4 * i];
    }
    const float* w1 = (const float*)d_in[21];
    const float* b1 = (const float*)d_in[22];
    const float* w2 = (const float*)d_in[23];
    const float* b2 = (const float*)d_in[24];
    const float* w3 = (const float*)d_in[25];
    const float* b3 = (const float*)d_in[26];

    float* ws = nullptr;
    hipGetSymbolAddress((void**)&ws, HIP_SYMBOL(g_ws));
    unsigned short* act = nullptr;
    hipGetSymbolAddress((void**)&act, HIP_SYMBOL(g_act));
    unsigned short* wb = nullptr;
    hipGetSymbolAddress((void**)&wb, HIP_SYMBOL(g_wb));

    float* part = ws + PART_OFF;
    float* pre  = ws + PRE_OFF;
    float* out5 = ws + OUT5_OFF;
    float* h    = ws + H_OFF;
    float* bnp  = ws + BNP_OFF;       // 5 regions x 49152
    float* h1   = ws + H1_OFF;
    float* st   = ws + ST_OFF;
    // fuse-phase scratch (dead before convs): tbuf 22.15MB at ws+0, Wlin 5.3MB after
    unsigned short* tbuf = (unsigned short*)ws;
    unsigned short* wlin = tbuf + (size_t)2 * 10816 * 512;   // 11,075,584 ushorts

    unsigned short* xin = act + XIN_OFF;
    unsigned short* a1  = act + A1_OFF;
    unsigned short* a2  = act + A2_OFF;
    unsigned short* a3  = act + A3_OFF;
    unsigned short* a4  = act + A4_OFF;

    static const int KF[5] = {81, 648, 1296, 2592, 5184};
    static const int CO[5] = {24, 48, 96, 192, 384};
    static const int CP[5] = {4, 24, 48, 96, 192};
    static const int KP[5] = {128, 672, 1312, 2592, 5184};
    static const int APAD[5] = {64, 64, 128, 192, 384};          // alphaT padded rows
    static const int PPAD[5] = {128, 704, 1344, 2624, 5184};     // projT padded rows (KT*64)
    static const int KT[5] = {2, 11, 21, 41, 81};                // k-tiles
    static const int OT[5] = {1, 1, 2, 3, 6};                    // o-tiles (64-wide)
    static const int NOFT[5] = {2, 3, 6, 12, 24};                // o-frags = ceil(CO/16)
    static const int NPAD[5] = {32, 48, 96, 192, 384};           // Wlin rows (noft*16)

    // ---- merged init + prep (one dispatch) ----
    InitPrepArgs ip;
    Fuse3Args f3;
    ReordBArgs rb;
    int prepBlocks = 0;
    {
        int row = 0, blk = 0;
        ip.start[0] = 0;
        for (int i = 0; i < 5; ++i) {
            ip.src[i] = al[i]; ip.W[i] = CO[i]; ip.dstrow[i] = row;
            f3.aoff[i] = row;
            row += APAD[i];
            blk += (APAD[i] / 64) * 16;
            ip.start[i + 1] = blk;
        }
        for (int i = 0; i < 5; ++i) {
            ip.src[5 + i] = p[i]; ip.W[5 + i] = KF[i]; ip.dstrow[5 + i] = row;
            f3.poff[i] = row;
            row += PPAD[i];
            blk += (PPAD[i] / 64) * 16;
            ip.start[5 + i + 1] = blk;
        }
        ip.rowtot = row;   // 10816
        f3.rowtot = row;
        prepBlocks = blk;  // 2704
        ip.prepBlocks = prepBlocks;
        ip.x = x; ip.xp = xin; ip.bnp = bnp;
        ip.zp = (int4*)(act + A1_OFF);
        ip.nz = (int)((AR_TOT - A1_OFF) * 2 / 16);
        ip.wbz = (int4*)wb;
        ip.nwb = (int)(WB_TOT * 2 / 16);
        const int initBlocks = (1871424 + 255) / 256;   // 7311
        init_prep<<<prepBlocks + initBlocks, 256, 0, stream>>>(ip, tbuf);
    }

    // ---- fuse GEMM (split-bf16 3-pass, LDS-staged 2-phase) -> bf16 Wlin ----
    {
        int s0 = 0, woff = 0;
        for (int i = 0; i < 5; ++i) {
            f3.woff[i] = woff;
            f3.KL[i] = KT[i] * 64;
            f3.noft[i] = NOFT[i];
            f3.kt[i] = KT[i];
            f3.start[i] = s0;
            s0 += OT[i] * KT[i];
            woff += NPAD[i] * KT[i] * 64;
        }
        f3.start[5] = s0;   // 664 blocks
        fuse_mfma<<<s0, 256, 0, stream>>>(tbuf, wlin, f3);
    }

    // ---- reorder: Wlin -> Wb (coalesced row writes) ----
    {
        int s0 = 0, woff = 0;
        for (int i = 0; i < 5; ++i) {
            rb.woff[i] = woff;
            rb.wboff[i] = (int)WB_OFF[i];
            rb.K[i] = KF[i]; rb.KL[i] = KT[i] * 64; rb.KP[i] = KP[i]; rb.CP[i] = CP[i];
            rb.start[i] = s0;
            s0 += CO[i];
            woff += NPAD[i] * KT[i] * 64;
        }
        rb.start[5] = s0;
        reorder_b<<<s0, 256, 0, stream>>>(wlin, wb, rb);
    }

    // ---- L1 ----  M=401408 -> 3136 blocks of 128 rows
    conv_mfma<4, 24, 128, 112, 112, 56, 56, 32, 1>
        <<<dim3(3136, 1), 256, 0, stream>>>(xin, wb + WB_OFF[0], pre, nullptr, bnp);
    bn_reduce<<<24, 64, 0, stream>>>(bnp, g[0], q[0], st, 1.f / 100352.f);
    bn_apply_halo<24, 56, 56><<<9408, 256, 0, stream>>>(pre, st, a1);

    // ---- L2 ----  M=100352 -> 784
    conv_mfma<24, 48, 672, 56, 56, 28, 28, 48, 1>
        <<<dim3(784, 1), 256, 0, stream>>>(a1, wb + WB_OFF[1], pre, nullptr, bnp + 49152);
    bn_reduce<<<48, 64, 0, stream>>>(bnp + 49152, g[1], q[1], st, 1.f / 25088.f);
    bn_apply_halo<48, 28, 28><<<4704, 256, 0, stream>>>(pre, st, a2);

    // ---- L3 ----  M=25088 -> 196
    conv_mfma<48, 96, 1312, 28, 28, 14, 14, 48, 1>
        <<<dim3(196, 2), 256, 0, stream>>>(a2, wb + WB_OFF[2], pre, nullptr, bnp + 2 * 49152);
    bn_reduce<<<96, 64, 0, stream>>>(bnp + 2 * 49152, g[2], q[2], st, 1.f / 6272.f);
    bn_apply_halo<96, 14, 14><<<2352, 256, 0, stream>>>(pre, st, a3);

    // ---- L4 (split-K 3) ----  M=6272 -> 49
    conv_mfma<96, 192, 2592, 14, 14, 7, 7, 64, 3>
        <<<dim3(49, 3, 3), 256, 0, stream>>>(a3, wb + WB_OFF[3], nullptr, part, nullptr);
    pool_epi<192, 7, 7, 3><<<1176, 256, 0, stream>>>(part, pre, bnp + 3 * 49152);
    bn_reduce<<<192, 64, 0, stream>>>(bnp + 3 * 49152, g[3], q[3], st, 1.f / 1568.f);
    bn_apply_halo<192, 7, 7><<<1176, 256, 0, stream>>>(pre, st, a4);

    // ---- L5 (split-K 6) ----  M=1152 -> 9
    conv_mfma<192, 384, 5184, 7, 7, 3, 3, 64, 6>
        <<<dim3(9, 6, 6), 256, 0, stream>>>(a4, wb + WB_OFF[4], nullptr, part, nullptr);
    pool_epi<384, 3, 3, 6><<<432, 256, 0, stream>>>(part, out5, bnp + 4 * 49152);
    bn_reduce<<<384, 64, 0, stream>>>(bnp + 4 * 49152, g[4], q[4], st, 1.f / 288.f);

    // ---- head ----
    transpose5<<<432, 256, 0, stream>>>(out5, st, h);
    fc1_k<<<512, 256, 0, stream>>>(h, w1, b1, h1);
    fc23_k<<<1, 256, 0, stream>>>(h1, w2, b2, w3, b3, (float*)d_out);
}